// Round 3
// baseline (482.152 us; speedup 1.0000x reference)
//
#include <hip/hip_runtime.h>

// Native clang vector type — accepted by __builtin_nontemporal_load/store
typedef float vf4 __attribute__((ext_vector_type(4)));

// Workspace layout (float offsets). ws[0..3] = barrier counter (uint), memset to 0
// by a captured memset node each replay (ws is harness-poisoned between batches).
#define WS_FPART 16     // fpart[4][128]
#define WS_H1    528    // h1[450]
#define WS_FEAT  1040   // feat[450]
#define WS_H2    1552   // h2[450]

#define NBLK 512        // k_front grid; 2/CU co-resident (guaranteed by launch_bounds)
#define NACT 113        // blocks active in the 450-row matvec phases

// Monotonic-counter grid barrier. All NBLK blocks are co-resident
// (__launch_bounds__(256,2): VGPR<=256, LDS 5.2KB -> 2 blocks/CU x 256 CU = 512),
// so arrival-count spin cannot deadlock. ACQ_REL/ACQUIRE at agent scope handles
// cross-XCD L2 non-coherence (writeback on release, invalidate on acquire).
__device__ __forceinline__ void gbar(unsigned* ctr, unsigned target) {
  __syncthreads();
  if (threadIdx.x == 0) {
    __hip_atomic_fetch_add(ctr, 1u, __ATOMIC_ACQ_REL, __HIP_MEMORY_SCOPE_AGENT);
    while (__hip_atomic_load(ctr, __ATOMIC_ACQUIRE, __HIP_MEMORY_SCOPE_AGENT) < target)
      __builtin_amdgcn_s_sleep(2);
  }
  __syncthreads();
}

// Relaxed agent-scope accessors for cross-block intermediates (bypass stale L1/L2).
__device__ __forceinline__ float aload(const float* p) {
  return __hip_atomic_load(p, __ATOMIC_RELAXED, __HIP_MEMORY_SCOPE_AGENT);
}
__device__ __forceinline__ void astore(float* p, float v) {
  __hip_atomic_store(p, v, __ATOMIC_RELAXED, __HIP_MEMORY_SCOPE_AGENT);
}

// Fused front: k_f + k_h1 + k_mv450(eW2) + k_mv450(dW1,relu) with grid barriers.
// Phase 1 uses all 512 blocks (one (i,t) tile each, identical to old k_f).
// Phases 2-4 use blocks 0..112 (wave per 450-row), identical math to old kernels.
__global__ __launch_bounds__(256, 2) void k_front(
    const float* __restrict__ x, const float* __restrict__ TwE,
    const float* __restrict__ PE, const float* __restrict__ CE,
    const float* __restrict__ mE,
    const float* __restrict__ eW1, const float* __restrict__ eb1,
    const float* __restrict__ eW2, const float* __restrict__ eb2,
    const float* __restrict__ dW1, const float* __restrict__ db1,
    unsigned* __restrict__ bar, float* __restrict__ ws) {
  float* fpart = ws + WS_FPART;
  float* h1    = ws + WS_H1;
  float* feat  = ws + WS_FEAT;
  float* h2    = ws + WS_H2;
  const int tid  = threadIdx.x;
  const int b    = blockIdx.x;
  const int lane = tid & 63;
  const int wv   = tid >> 6;

  __shared__ float sCE[128];
  __shared__ float coef[256];
  __shared__ float red[4];
  __shared__ float svec[450];    // input vector of current matvec phase
  __shared__ float sfeat0[450];  // feat0 (redundant per active block)

  // ---- Phase 1: fpart[t][i] = sum_{p,c} x[4+t,p,c]*TwE[t,i]*PE[p,i]*CE[c,i]
  {
    const int i = b >> 2;
    const int t = b & 3;
    const float tw = TwE[t * 128 + i];          // wave-uniform scalar load
    if (tid < 128) sCE[tid] = CE[tid * 128 + i];
    coef[tid] = tw * PE[tid * 128 + i];
    __syncthreads();
    const float2 ce = ((const float2*)sCE)[lane];
    const float2* Xw = (const float2*)(x + 4 * 256 * 128);   // window start
    float acc = 0.f;
    const int l0 = wv * 64;
#pragma unroll 8
    for (int k = 0; k < 64; ++k) {
      int l = l0 + k;                 // p index
      int q = (t << 8) + l;           // global (t,p) row in window
      float2 v = Xw[q * 64 + lane];   // coalesced 512B wave load (L2-broadcast)
      acc += coef[l] * (v.x * ce.x + v.y * ce.y);
    }
#pragma unroll
    for (int off = 32; off > 0; off >>= 1) acc += __shfl_down(acc, off);
    if (lane == 0) red[wv] = acc;
    __syncthreads();
    if (tid == 0) astore(&fpart[t * 128 + i], red[0] + red[1] + red[2] + red[3]);
  }
  gbar(bar, NBLK);

  const int row = b * 4 + wv;   // output row for phases 2-4 (valid when b < NACT)

  // ---- Phase 2: sf = sum_t fpart; feat0 = mE @ sf (redundant); h1 rows
  if (b < NACT) {
    if (tid < 128)
      svec[tid] = (aload(&fpart[tid]) + aload(&fpart[128 + tid]))
                + (aload(&fpart[256 + tid]) + aload(&fpart[384 + tid]));
    __syncthreads();
    for (int r = tid; r < 450; r += 256) {
      const float4* mrow = (const float4*)(mE + r * 128);  // 512B row via L1/L2
      float a0 = 0.f, a1 = 0.f, a2 = 0.f, a3 = 0.f;
#pragma unroll 8
      for (int k = 0; k < 32; ++k) {
        float4 m = mrow[k];
        a0 += m.x * svec[4 * k];       // LDS same-address broadcast
        a1 += m.y * svec[4 * k + 1];
        a2 += m.z * svec[4 * k + 2];
        a3 += m.w * svec[4 * k + 3];
      }
      sfeat0[r] = (a0 + a1) + (a2 + a3);
    }
    __syncthreads();
    if (row < 450) {
      const float2* Wr = (const float2*)(eW1 + row * 450);
      float acc = 0.f;
#pragma unroll
      for (int k = 0; k < 4; ++k) {
        int idx = lane + (k << 6);
        if (idx < 225) {
          float2 w = Wr[idx];
          acc += w.x * sfeat0[2 * idx] + w.y * sfeat0[2 * idx + 1];
        }
      }
#pragma unroll
      for (int off = 32; off > 0; off >>= 1) acc += __shfl_down(acc, off);
      if (lane == 0) astore(&h1[row], fmaxf(acc + eb1[row], 0.f));
    }
  }
  gbar(bar, 2 * NBLK);

  // ---- Phase 3: feat = eW2 @ h1 + eb2
  if (b < NACT) {
    if (tid < 450) svec[tid] = aload(&h1[tid]);
    if (tid + 256 < 450) svec[tid + 256] = aload(&h1[tid + 256]);
    __syncthreads();
    if (row < 450) {
      const float2* Wr = (const float2*)(eW2 + row * 450);
      float acc = 0.f;
#pragma unroll
      for (int k = 0; k < 4; ++k) {
        int idx = lane + (k << 6);
        if (idx < 225) {
          float2 w = Wr[idx];
          acc += w.x * svec[2 * idx] + w.y * svec[2 * idx + 1];
        }
      }
#pragma unroll
      for (int off = 32; off > 0; off >>= 1) acc += __shfl_down(acc, off);
      if (lane == 0) astore(&feat[row], acc + eb2[row]);
    }
  }
  gbar(bar, 3 * NBLK);

  // ---- Phase 4: h2 = relu(dW1 @ feat + db1)
  if (b < NACT) {
    if (tid < 450) svec[tid] = aload(&feat[tid]);
    if (tid + 256 < 450) svec[tid + 256] = aload(&feat[tid + 256]);
    __syncthreads();
    if (row < 450) {
      const float2* Wr = (const float2*)(dW1 + row * 450);
      float acc = 0.f;
#pragma unroll
      for (int k = 0; k < 4; ++k) {
        int idx = lane + (k << 6);
        if (idx < 225) {
          float2 w = Wr[idx];
          acc += w.x * svec[2 * idx] + w.y * svec[2 * idx + 1];
        }
      }
#pragma unroll
      for (int off = 32; off > 0; off >>= 1) acc += __shfl_down(acc, off);
      if (lane == 0) astore(&h2[row], fmaxf(acc + db1[row], 0.f));
    }
  }
  // kernel boundary provides release; k_dec2 reads h2 normally
}

// K6: out = dec_W2 @ h2 + dec_b2. Wave per ROW-PAIR (225 float4, pair stride 3600B).
// CACHED weight loads (NT removed): dec_W2 = 225 MiB < 256 MiB Infinity Cache, so
// across the ~80 graph replays per reset the L3 retains it — NT was forfeiting that.
// NT stores kept for out (no reuse).
__global__ __launch_bounds__(512) void k_dec2(
    const float* __restrict__ W, const float* __restrict__ b,
    const float* __restrict__ h, float* __restrict__ out) {
  __shared__ float sv2[900];
  const int tid = threadIdx.x;
  for (int k = tid; k < 900; k += 512) sv2[k] = h[k < 450 ? k : k - 450];
  __syncthreads();
  const int lane = tid & 63;
  const int rp = blockIdx.x * 8 + (tid >> 6);    // row pair, 0..65535
  const vf4* Wp = (const vf4*)(W + (size_t)rp * 900);
  float accA = 0.f, accB = 0.f;
#pragma unroll
  for (int k = 0; k < 3; ++k) {
    int j = lane + (k << 6);          // 0..191
    vf4 w = Wp[j];                    // cached load — allow L3 retention
    const float* s = &sv2[4 * j];
    float p01 = w.x * s[0] + w.y * s[1];
    float p23 = w.z * s[2] + w.w * s[3];
    if (4 * j + 3 < 450)      accA += p01 + p23;   // j <= 111
    else if (4 * j >= 450)    accB += p01 + p23;   // j >= 113
    else { accA += p01; accB += p23; }             // j == 112 straddles
  }
  if (lane < 33) {                    // j = 192..224, all row B
    int j = 192 + lane;
    vf4 w = Wp[j];                    // cached load
    const float* s = &sv2[4 * j];
    accB += w.x * s[0] + w.y * s[1] + w.z * s[2] + w.w * s[3];
  }
#pragma unroll
  for (int off = 32; off > 0; off >>= 1) {
    accA += __shfl_down(accA, off);
    accB += __shfl_down(accB, off);
  }
  if (lane == 0) {
    int r = rp * 2;
    __builtin_nontemporal_store(accA + b[r],     &out[r]);
    __builtin_nontemporal_store(accB + b[r + 1], &out[r + 1]);
  }
}

extern "C" void kernel_launch(void* const* d_in, const int* in_sizes, int n_in,
                              void* d_out, int out_size, void* d_ws, size_t ws_size,
                              hipStream_t stream) {
  const float* x   = (const float*)d_in[0];
  const float* TwE = (const float*)d_in[2];
  const float* PE  = (const float*)d_in[3];
  const float* CE  = (const float*)d_in[4];
  const float* mE  = (const float*)d_in[5];
  const float* eW1 = (const float*)d_in[6];
  const float* eb1 = (const float*)d_in[7];
  const float* eW2 = (const float*)d_in[8];
  const float* eb2 = (const float*)d_in[9];
  const float* dW1 = (const float*)d_in[10];
  const float* db1 = (const float*)d_in[11];
  const float* dW2 = (const float*)d_in[12];
  const float* db2 = (const float*)d_in[13];
  float* out = (float*)d_out;
  float* ws  = (float*)d_ws;
  unsigned* bar = (unsigned*)d_ws;

  // Zero the grid-barrier counter every replay (ws is poisoned between batches).
  // hipMemsetAsync is graph-capturable (memset node) and not on the banned list.
  hipMemsetAsync(d_ws, 0, 16, stream);
  k_front<<<NBLK, 256, 0, stream>>>(x, TwE, PE, CE, mE,
                                    eW1, eb1, eW2, eb2, dW1, db1, bar, ws);
  k_dec2 <<<8192, 512, 0, stream>>>(dW2, db2, ws + WS_H2, out);
}

// Round 5
// 441.967 us; speedup vs baseline: 1.0909x; 1.0909x over previous
//
#include <hip/hip_runtime.h>

// Native clang vector type — accepted by __builtin_nontemporal_load/store
typedef float vf4 __attribute__((ext_vector_type(4)));

// Workspace float offsets
#define WS_FPART 0      // fpart[4][128]
#define WS_H2    512    // h2[450]

// K1: fpart[t][i] = sum_{p,c} x[4+t,p,c] * TwE[t,i] * PE[p,i] * CE[c,i]
// 512 blocks = 4 per output i (one per t). Per-block L2-broadcast read = 128 KB.
__global__ __launch_bounds__(256) void k_f(
    const float* __restrict__ x, const float* __restrict__ TwE,
    const float* __restrict__ PE, const float* __restrict__ CE,
    float* __restrict__ fpart) {
  const int i = blockIdx.x >> 2;
  const int t = blockIdx.x & 3;
  const int tid = threadIdx.x;
  __shared__ float sCE[128];
  __shared__ float coef[256];   // coef[p] = TwE[t,i] * PE[p,i]
  __shared__ float red[4];
  const float tw = TwE[t * 128 + i];     // wave-uniform scalar load
  if (tid < 128) sCE[tid] = CE[tid * 128 + i];
  coef[tid] = tw * PE[tid * 128 + i];
  __syncthreads();
  const int lane = tid & 63;
  const int wv = tid >> 6;
  const float2 ce = ((const float2*)sCE)[lane];
  const float2* Xw = (const float2*)(x + 4 * 256 * 128);  // window start
  float acc = 0.f;
  const int l0 = wv * 64;                // each wave: 64 of this block's 256 p-rows
#pragma unroll 8
  for (int k = 0; k < 64; ++k) {
    int l = l0 + k;                      // p index
    int q = (t << 8) + l;                // global (t,p) row in window
    float2 v = Xw[q * 64 + lane];        // coalesced 512B wave load
    acc += coef[l] * (v.x * ce.x + v.y * ce.y);
  }
#pragma unroll
  for (int off = 32; off > 0; off >>= 1) acc += __shfl_down(acc, off);
  if (lane == 0) red[wv] = acc;
  __syncthreads();
  if (tid == 0) fpart[t * 128 + i] = red[0] + red[1] + red[2] + red[3];
}

// K2: fused middle chain via REDUNDANT COMPUTE (no cross-block deps, no barriers):
// each of 113 blocks computes sf, feat0 = mE@sf (all 450), h1 = relu(eW1@feat0+b)
// (all 450, thread-per-row through L1/L2), feat = eW2@h1+b (all 450), then ONLY its
// own 4 rows of h2 = relu(dW1@feat+b). Per-block reads ~1.85 MB, all L2-cacheable.
__global__ __launch_bounds__(256) void k_rest(
    const float* __restrict__ fpart, const float* __restrict__ mE,
    const float* __restrict__ eW1, const float* __restrict__ eb1,
    const float* __restrict__ eW2, const float* __restrict__ eb2,
    const float* __restrict__ dW1, const float* __restrict__ db1,
    float* __restrict__ h2) {
  __shared__ float sf[128];
  __shared__ float sfeat0[450];
  __shared__ float sh1[450];
  __shared__ float sfeat[450];
  const int tid = threadIdx.x;
  if (tid < 128)
    sf[tid] = (fpart[tid] + fpart[128 + tid]) + (fpart[256 + tid] + fpart[384 + tid]);
  __syncthreads();
  // feat0 = mE @ sf  (thread-per-row, 512B float4 rows)
  for (int r = tid; r < 450; r += 256) {
    const float4* row = (const float4*)(mE + r * 128);
    float a0 = 0.f, a1 = 0.f, a2 = 0.f, a3 = 0.f;
#pragma unroll 8
    for (int k = 0; k < 32; ++k) {
      float4 m = row[k];
      a0 += m.x * sf[4 * k];       // LDS same-address broadcast
      a1 += m.y * sf[4 * k + 1];
      a2 += m.z * sf[4 * k + 2];
      a3 += m.w * sf[4 * k + 3];
    }
    sfeat0[r] = (a0 + a1) + (a2 + a3);
  }
  __syncthreads();
  // h1 = relu(eW1 @ feat0 + eb1) — ALL rows (redundant per block). Rows are
  // 1800 B (float2-aligned only). Per-thread sequential row stream: 8 float2
  // per 64B line -> L1 amortizes the uncoalesced lane pattern.
  for (int r = tid; r < 450; r += 256) {
    const float2* row = (const float2*)(eW1 + r * 450);
    float a0 = 0.f, a1 = 0.f;
#pragma unroll 5
    for (int k = 0; k < 225; ++k) {
      float2 w = row[k];
      a0 += w.x * sfeat0[2 * k];
      a1 += w.y * sfeat0[2 * k + 1];
    }
    sh1[r] = fmaxf(a0 + a1 + eb1[r], 0.f);
  }
  __syncthreads();
  // feat = eW2 @ h1 + eb2 — ALL rows (redundant per block)
  for (int r = tid; r < 450; r += 256) {
    const float2* row = (const float2*)(eW2 + r * 450);
    float a0 = 0.f, a1 = 0.f;
#pragma unroll 5
    for (int k = 0; k < 225; ++k) {
      float2 w = row[k];
      a0 += w.x * sh1[2 * k];
      a1 += w.y * sh1[2 * k + 1];
    }
    sfeat[r] = a0 + a1 + eb2[r];
  }
  __syncthreads();
  // h2: own 4 rows only, wave per row (same as old k_mv450)
  const int lane = tid & 63;
  const int row = blockIdx.x * 4 + (tid >> 6);
  if (row < 450) {
    const float2* Wr = (const float2*)(dW1 + row * 450);
    float acc = 0.f;
#pragma unroll
    for (int k = 0; k < 4; ++k) {
      int idx = lane + (k << 6);
      if (idx < 225) {
        float2 w = Wr[idx];
        acc += w.x * sfeat[2 * idx] + w.y * sfeat[2 * idx + 1];
      }
    }
#pragma unroll
    for (int off = 32; off > 0; off >>= 1) acc += __shfl_down(acc, off);
    if (lane == 0) h2[row] = fmaxf(acc + db1[row], 0.f);
  }
}

// K3: out = dec_W2 @ h2 + dec_b2. Wave per ROW-PAIR (225 float4, 16B-aligned:
// pair stride 3600B). NT loads/stores (the 900-MiB poison fills flush the LLC
// every replay, so dec_W2 can never be retained — stream it). Round-0-identical.
__global__ __launch_bounds__(512) void k_dec2(
    const float* __restrict__ W, const float* __restrict__ b,
    const float* __restrict__ h, float* __restrict__ out) {
  __shared__ float sv2[900];
  const int tid = threadIdx.x;
  for (int k = tid; k < 900; k += 512) sv2[k] = h[k < 450 ? k : k - 450];
  __syncthreads();
  const int lane = tid & 63;
  const int rp = blockIdx.x * 8 + (tid >> 6);    // row pair, 0..65535
  const vf4* Wp = (const vf4*)(W + (size_t)rp * 900);
  float accA = 0.f, accB = 0.f;
#pragma unroll
  for (int k = 0; k < 3; ++k) {
    int j = lane + (k << 6);          // 0..191
    vf4 w = __builtin_nontemporal_load(&Wp[j]);
    const float* s = &sv2[4 * j];
    float p01 = w.x * s[0] + w.y * s[1];
    float p23 = w.z * s[2] + w.w * s[3];
    if (4 * j + 3 < 450)      accA += p01 + p23;   // j <= 111
    else if (4 * j >= 450)    accB += p01 + p23;   // j >= 113
    else { accA += p01; accB += p23; }             // j == 112 straddles
  }
  if (lane < 33) {                    // j = 192..224, all row B
    int j = 192 + lane;
    vf4 w = __builtin_nontemporal_load(&Wp[j]);
    const float* s = &sv2[4 * j];
    accB += w.x * s[0] + w.y * s[1] + w.z * s[2] + w.w * s[3];
  }
#pragma unroll
  for (int off = 32; off > 0; off >>= 1) {
    accA += __shfl_down(accA, off);
    accB += __shfl_down(accB, off);
  }
  if (lane == 0) {
    int r = rp * 2;
    __builtin_nontemporal_store(accA + b[r],     &out[r]);
    __builtin_nontemporal_store(accB + b[r + 1], &out[r + 1]);
  }
}

extern "C" void kernel_launch(void* const* d_in, const int* in_sizes, int n_in,
                              void* d_out, int out_size, void* d_ws, size_t ws_size,
                              hipStream_t stream) {
  const float* x   = (const float*)d_in[0];
  const float* TwE = (const float*)d_in[2];
  const float* PE  = (const float*)d_in[3];
  const float* CE  = (const float*)d_in[4];
  const float* mE  = (const float*)d_in[5];
  const float* eW1 = (const float*)d_in[6];
  const float* eb1 = (const float*)d_in[7];
  const float* eW2 = (const float*)d_in[8];
  const float* eb2 = (const float*)d_in[9];
  const float* dW1 = (const float*)d_in[10];
  const float* db1 = (const float*)d_in[11];
  const float* dW2 = (const float*)d_in[12];
  const float* db2 = (const float*)d_in[13];
  float* out = (float*)d_out;
  float* ws  = (float*)d_ws;

  k_f   <<<512,  256, 0, stream>>>(x, TwE, PE, CE, ws + WS_FPART);
  k_rest<<<113,  256, 0, stream>>>(ws + WS_FPART, mE, eW1, eb1, eW2, eb2,
                                   dW1, db1, ws + WS_H2);
  k_dec2<<<8192, 512, 0, stream>>>(dW2, db2, ws + WS_H2, out);
}